// Round 9
// baseline (30.433 us; speedup 1.0000x reference)
//
#include <hip/hip_runtime.h>

// LaplacianLossBatch: B=16, NV=2562, NF=5120
// Exact reference semantics (verified: absmax 0.0 in R1-R8):
//   A[i,j] = 1 iff pair (i,j) set by any face (6 ordered pairs/face, SET semantics)
//   deg[i] = popcount(row i of A)  (diagonal bit included — degenerate faces)
//   v_avg[i] = deg>0 ? v[i] - (sum_{j!=i, A[i,j]} v[j]) / deg : 0
//   out = sum(v_avg^2)
//
// R6: fused LDS-tiled kernel + reduce kernel (18.9us).
// R7: cooperative grid.sync FAILED (~120us spin across 8 XCDs). Reverted.
// R8: int4 face loads + TILE=96: 18.5us — flat. Kernel work no longer moves
//     dur_us; floor is dispatch structure (~13us fixed).
// R9: kill the lap_reduce kernel node. Last-block-done reduction inside
//     lap_fused (store partial -> threadfence -> atomicAdd counter; the
//     432nd block acquires and folds partials into d_out in fixed order).
//     Counter zeroed per call by a 4-byte hipMemsetAsync node (d_ws is
//     poisoned once and never re-poisoned between replays).

constexpr int NV = 2562;
constexpr int NF = 5120;
constexpr int BATCH = 16;
constexpr int W = (NV + 31) / 32;            // 81 words per bitmask row
constexpr int TILE = 96;                     // rows per block
constexpr int NT = (NV + TILE - 1) / TILE;   // 27 tiles (last tile: 66 rows)
constexpr int THREADS = 512;                 // 8 waves
constexpr int NPART = NT * BATCH;            // 432 partials

static_assert(TILE % 32 == 0, "phase-2 pass structure");
static_assert(NPART <= THREADS, "one-shot last-block reduce");
static_assert(TILE * W * 4 + NV * 3 * 4 + 64 < 64 * 1024, "static LDS limit");

__global__ __launch_bounds__(THREADS)
void lap_fused(const float* __restrict__ vertices,
               const int* __restrict__ faces,
               float* __restrict__ partial,
               unsigned int* __restrict__ counter,
               float* __restrict__ out) {
    __shared__ unsigned int m[TILE * W];             // 31104 B
    __shared__ __align__(16) float vsh[NV * 3];      // 30744 B
    __shared__ float red[THREADS / 64];
    __shared__ unsigned int lastFlag;

    const int tile = blockIdx.x;
    const int b    = blockIdx.y;
    const int v0   = tile * TILE;
    const int tid  = threadIdx.x;

    // phase 0: clear LDS mask + stage this batch's vertices (float2: the
    // per-batch base (b*30744 bytes) is only 8B-aligned for odd b)
    for (int k = tid; k < TILE * W; k += THREADS) m[k] = 0u;
    const float2* vb2 = (const float2*)(vertices + (size_t)b * NV * 3);
    float2* vsh2 = (float2*)vsh;
    constexpr int NV3_2 = (NV * 3) / 2;              // 3843 float2, exact
    for (int k = tid; k < NV3_2; k += THREADS) vsh2[k] = vb2[k];
    __syncthreads();

    // phase 1: int4 face loads — 3 dwordx4 = 4 faces. Per-batch base is
    // b*61440 bytes: 16B-aligned. Indices fully unrolled -> static regs.
    const int4* fb4 = (const int4*)(faces + (size_t)b * NF * 3);
    constexpr int NQ = NF / 4;                       // 1280 face-quads
    for (int q = tid; q < NQ; q += THREADS) {
        int4 a = fb4[3 * q], c = fb4[3 * q + 1], d = fb4[3 * q + 2];
        const int v[12] = {a.x, a.y, a.z, a.w, c.x, c.y, c.z, c.w,
                           d.x, d.y, d.z, d.w};
        auto setb = [&](int s, int dd) {
            unsigned r = (unsigned)(s - v0);
            if (r < (unsigned)TILE)
                atomicOr(&m[r * W + (dd >> 5)], 1u << (dd & 31));
        };
        #pragma unroll
        for (int ff = 0; ff < 4; ++ff) {
            int i0 = v[3 * ff], i1 = v[3 * ff + 1], i2 = v[3 * ff + 2];
            setb(i0, i1); setb(i1, i0);
            setb(i1, i2); setb(i2, i1);
            setb(i2, i0); setb(i0, i2);
        }
    }
    __syncthreads();

    // phase 2: 4 rows per wave, 16 lanes per row; TILE/32 passes.
    const int lane = tid & 63;
    const int wid  = tid >> 6;
    const int g    = lane >> 4;      // row group within wave (0..3)
    const int s    = lane & 15;      // sublane within row group
    const int rows = min(TILE, NV - v0);
    float acc = 0.f;                 // nonzero only on s==0 lanes

    #pragma unroll
    for (int pass = 0; pass < TILE / 32; ++pass) {
        int r = pass * 32 + wid * 4 + g;
        float deg = 0.f, sx = 0.f, sy = 0.f, sz = 0.f;
        int i = v0 + r;
        if (r < rows) {
            const unsigned int* row = &m[r * W];
            for (int w = s; w < W; w += 16) {
                unsigned bits = row[w];
                deg += (float)__popc(bits);
                while (bits) {
                    int bno = __ffs(bits) - 1;
                    bits &= bits - 1;
                    int j = w * 32 + bno;
                    if (j != i) {    // diagonal in deg, not in neighbor sum
                        sx += vsh[3 * j];
                        sy += vsh[3 * j + 1];
                        sz += vsh[3 * j + 2];
                    }
                }
            }
        }
        // reduce within each 16-lane group (xor 1,2,4,8 stays in-group)
        #pragma unroll
        for (int off = 1; off <= 8; off <<= 1) {
            deg += __shfl_xor(deg, off);
            sx  += __shfl_xor(sx,  off);
            sy  += __shfl_xor(sy,  off);
            sz  += __shfl_xor(sz,  off);
        }
        if (s == 0 && r < rows && deg > 0.5f) {
            float inv = 1.f / deg;
            float ax = vsh[3 * i]     - sx * inv;
            float ay = vsh[3 * i + 1] - sy * inv;
            float az = vsh[3 * i + 2] - sz * inv;
            acc += ax * ax + ay * ay + az * az;
        }
    }
    // fold the 4 group-lanes (0,16,32,48); other lanes carry 0
    acc += __shfl_xor(acc, 16);
    acc += __shfl_xor(acc, 32);
    if (lane == 0) red[wid] = acc;
    __syncthreads();
    if (tid == 0) {
        float t = 0.f;
        #pragma unroll
        for (int k = 0; k < THREADS / 64; ++k) t += red[k];
        partial[(size_t)b * NT + tile] = t;          // plain store
        __threadfence();                             // release partial
        unsigned old = atomicAdd(counter, 1u);       // device-scope RMW
        lastFlag = (old == NPART - 1) ? 1u : 0u;
    }
    __syncthreads();

    if (lastFlag) {
        // last block of this replay: acquire + fold all partials.
        __threadfence();
        float local = 0.f;
        if (tid < NPART)
            local = atomicAdd(&partial[tid], 0.0f);  // coherent cross-XCD read
        #pragma unroll
        for (int off = 32; off; off >>= 1) local += __shfl_down(local, off);
        if (lane == 0) red[wid] = local;
        __syncthreads();
        if (tid == 0) {
            float sum = 0.f;
            #pragma unroll
            for (int k = 0; k < THREADS / 64; ++k) sum += red[k];
            out[0] = sum;
        }
    }
}

extern "C" void kernel_launch(void* const* d_in, const int* in_sizes, int n_in,
                              void* d_out, int out_size, void* d_ws, size_t ws_size,
                              hipStream_t stream) {
    const float* vertices = (const float*)d_in[0];
    const int*   faces    = (const int*)d_in[1];
    float*       out      = (float*)d_out;
    float*       partial  = (float*)d_ws;                       // 432 floats
    unsigned int* counter = (unsigned int*)((char*)d_ws + 4096); // own cache line

    // counter must be 0 at every call start (d_ws poisoned 0xAA once, never
    // re-poisoned between replays; the 4-byte fill is graph-capturable).
    hipMemsetAsync(counter, 0, sizeof(unsigned int), stream);

    lap_fused<<<dim3(NT, BATCH), THREADS, 0, stream>>>(
        vertices, faces, partial, counter, out);
}

// Round 10
// 18.273 us; speedup vs baseline: 1.6655x; 1.6655x over previous
//
#include <hip/hip_runtime.h>

// LaplacianLossBatch: B=16, NV=2562, NF=5120
// Exact reference semantics (verified: absmax 0.0 in R1-R9):
//   A[i,j] = 1 iff pair (i,j) set by any face (6 ordered pairs/face, SET semantics)
//   deg[i] = popcount(row i of A)  (diagonal bit included — degenerate faces)
//   v_avg[i] = deg>0 ? v[i] - (sum_{j!=i, A[i,j]} v[j]) / deg : 0
//   out = sum(v_avg^2)
//
// R6: fused LDS kernel + reduce kernel (18.9us).
// R7: cooperative grid.sync FAILED (~120us spin across 8 XCDs). Reverted.
// R8: int4 face loads + TILE=96 (18.5us) — kernel work barely moves dur_us.
// R9: hipMemsetAsync(4B) node FAILED — rocclr fill node has ~12us replay
//     cost (profiled 39.7us even for 4 bytes). Reverted to R8 structure.
// R10: R8 + mask rows padded to 82 words -> uint2 (ds_read_b64) mask reads
//     halve phase-2's dependent LDS chain (6 -> 3 per row); uint4 mask clear
//     (15 -> 4 iterations). Two kernel nodes, NO fill nodes.

constexpr int NV = 2562;
constexpr int NF = 5120;
constexpr int BATCH = 16;
constexpr int W  = (NV + 31) / 32;           // 81 real words per row
constexpr int W2 = 82;                       // padded row stride (even, word 81 = 0)
constexpr int TILE = 96;                     // rows per block
constexpr int NT = (NV + TILE - 1) / TILE;   // 27 tiles (last tile: 66 rows)
constexpr int THREADS = 512;                 // 8 waves
constexpr int NPART = NT * BATCH;            // 432 partials

static_assert(TILE % 32 == 0, "phase-2 pass structure");
static_assert((TILE * W2) % 4 == 0, "uint4 clear");
static_assert(TILE * W2 * 4 + NV * 3 * 4 + 64 < 64 * 1024, "static LDS limit");

__global__ __launch_bounds__(THREADS)
void lap_fused(const float* __restrict__ vertices,
               const int* __restrict__ faces,
               float* __restrict__ partial) {
    __shared__ __align__(16) unsigned int m[TILE * W2];  // 31488 B
    __shared__ __align__(16) float vsh[NV * 3];          // 30744 B
    __shared__ float red[THREADS / 64];

    const int tile = blockIdx.x;
    const int b    = blockIdx.y;
    const int v0   = tile * TILE;
    const int tid  = threadIdx.x;

    // phase 0: uint4 clear of LDS mask (incl. pad words) + float2 vertex stage
    {
        uint4* m4 = (uint4*)m;
        constexpr int M4 = TILE * W2 / 4;                // 1968
        uint4 z; z.x = z.y = z.z = z.w = 0u;
        for (int k = tid; k < M4; k += THREADS) m4[k] = z;
    }
    const float2* vb2 = (const float2*)(vertices + (size_t)b * NV * 3);
    float2* vsh2 = (float2*)vsh;
    constexpr int NV3_2 = (NV * 3) / 2;                  // 3843 float2, exact
    for (int k = tid; k < NV3_2; k += THREADS) vsh2[k] = vb2[k];
    __syncthreads();

    // phase 1: int4 face loads — 3 dwordx4 = 4 faces (base 16B-aligned).
    // Indices fully unrolled -> static regs (no scratch).
    const int4* fb4 = (const int4*)(faces + (size_t)b * NF * 3);
    constexpr int NQ = NF / 4;                           // 1280 face-quads
    for (int q = tid; q < NQ; q += THREADS) {
        int4 a = fb4[3 * q], c = fb4[3 * q + 1], d = fb4[3 * q + 2];
        const int v[12] = {a.x, a.y, a.z, a.w, c.x, c.y, c.z, c.w,
                           d.x, d.y, d.z, d.w};
        auto setb = [&](int s, int dd) {
            unsigned r = (unsigned)(s - v0);
            if (r < (unsigned)TILE)
                atomicOr(&m[r * W2 + (dd >> 5)], 1u << (dd & 31));
        };
        #pragma unroll
        for (int ff = 0; ff < 4; ++ff) {
            int i0 = v[3 * ff], i1 = v[3 * ff + 1], i2 = v[3 * ff + 2];
            setb(i0, i1); setb(i1, i0);
            setb(i1, i2); setb(i2, i1);
            setb(i2, i0); setb(i0, i2);
        }
    }
    __syncthreads();

    // phase 2: 4 rows/wave, 16 lanes/row; lane s reads word-PAIRS (uint2,
    // 8B-aligned: row stride 82 even, w even). Covers even w in [0,80];
    // odd words ride along as pair-partner; pad word 81 is zero.
    const int lane = tid & 63;
    const int wid  = tid >> 6;
    const int g    = lane >> 4;
    const int s    = lane & 15;
    const int rows = min(TILE, NV - v0);
    float acc = 0.f;                         // nonzero only on s==0 lanes

    #pragma unroll
    for (int pass = 0; pass < TILE / 32; ++pass) {
        int r = pass * 32 + wid * 4 + g;
        float deg = 0.f, sx = 0.f, sy = 0.f, sz = 0.f;
        int i = v0 + r;
        if (r < rows) {
            const unsigned int* row = &m[r * W2];
            for (int w = 2 * s; w < W; w += 32) {
                uint2 bb = *(const uint2*)&row[w];
                deg += (float)(__popc(bb.x) + __popc(bb.y));
                #pragma unroll
                for (int half = 0; half < 2; ++half) {
                    unsigned bits = half ? bb.y : bb.x;
                    int base = (w + half) * 32;
                    while (bits) {
                        int bno = __ffs(bits) - 1;
                        bits &= bits - 1;
                        int j = base + bno;
                        if (j != i) {  // diagonal in deg, not in neighbor sum
                            sx += vsh[3 * j];
                            sy += vsh[3 * j + 1];
                            sz += vsh[3 * j + 2];
                        }
                    }
                }
            }
        }
        // reduce within each 16-lane group (xor 1,2,4,8 stays in-group)
        #pragma unroll
        for (int off = 1; off <= 8; off <<= 1) {
            deg += __shfl_xor(deg, off);
            sx  += __shfl_xor(sx,  off);
            sy  += __shfl_xor(sy,  off);
            sz  += __shfl_xor(sz,  off);
        }
        if (s == 0 && r < rows && deg > 0.5f) {
            float inv = 1.f / deg;
            float ax = vsh[3 * i]     - sx * inv;
            float ay = vsh[3 * i + 1] - sy * inv;
            float az = vsh[3 * i + 2] - sz * inv;
            acc += ax * ax + ay * ay + az * az;
        }
    }
    // fold the 4 group-lanes (0,16,32,48); other lanes carry 0
    acc += __shfl_xor(acc, 16);
    acc += __shfl_xor(acc, 32);
    if (lane == 0) red[wid] = acc;
    __syncthreads();
    if (tid == 0) {
        float t = 0.f;
        #pragma unroll
        for (int k = 0; k < THREADS / 64; ++k) t += red[k];
        partial[(size_t)b * gridDim.x + tile] = t;   // plain store: poison-immune
    }
}

__global__ void lap_reduce(const float* __restrict__ partial, int n4,
                           float* __restrict__ out) {
    const float4* p4 = (const float4*)partial;
    float local = 0.f;
    for (int k = threadIdx.x; k < n4; k += blockDim.x) {
        float4 v = p4[k];
        local += (v.x + v.y) + (v.z + v.w);
    }
    #pragma unroll
    for (int off = 32; off; off >>= 1) local += __shfl_down(local, off);
    __shared__ float red[4];
    int lane = threadIdx.x & 63, wid = threadIdx.x >> 6;
    if (lane == 0) red[wid] = local;
    __syncthreads();
    if (threadIdx.x == 0) out[0] = red[0] + red[1] + red[2] + red[3];
}

extern "C" void kernel_launch(void* const* d_in, const int* in_sizes, int n_in,
                              void* d_out, int out_size, void* d_ws, size_t ws_size,
                              hipStream_t stream) {
    const float* vertices = (const float*)d_in[0];
    const int*   faces    = (const int*)d_in[1];
    float*       out      = (float*)d_out;
    float*       partial  = (float*)d_ws;    // NPART = 432 floats (1.7 KB)

    lap_fused<<<dim3(NT, BATCH), THREADS, 0, stream>>>(vertices, faces, partial);
    static_assert(NPART % 4 == 0, "reduce uses float4");
    lap_reduce<<<1, 256, 0, stream>>>(partial, NPART / 4, out);
}